// Round 6
// baseline (412.397 us; speedup 1.0000x reference)
//
#include <hip/hip_runtime.h>
#include <hip/hip_bf16.h>

// CentroidsFlowAD: out[row] = sqrt(max(||e||^2 + min_col(||c||^2 - 2 e.c), 0))
// rows = 32*3136 = 100352, cols = 2048 centroids, K = 1024.
//
// Fast path (needs ~112 MiB ws), fp8 e4m3 cross-term (row norms exact fp32):
//   1. rowsq_fp8pack on centroids -> c8 (packed fp8) + csq
//   2. rowsq_fp8pack on embeds    -> e8 (packed fp8) + esq
//   3. gemm_min_fp8: 128x128 tile, BK=128, 4 waves (64x64), double-buffered
//      LDS 64 KiB -> 2 blocks/CU, counted vmcnt(8).
//      R6 schedule: WAITVM -> B1 -> readfrags+MFMA (NO lgkm wall between:
//      compiler interleaves ds_read with MFMA via fine lgkmcnt) -> lgkm0 ->
//      B2 -> stage(kt+2 into just-read buf). B2 carries the write-after-read
//      guarantee that R5 wrongly enforced BEFORE the MFMAs (the 50% wall).
//   4. final_min: 16-way min + sqrt
// fp8 K-packed row layout (128B per K-tile of 128): 16B slot s=ksp*4+g holds
// k = {32*(2ksp)+8g..+7 | 32*(2ksp+1)+8g..+7} -> lane (g,lr) b128 = both
// MFMA operands of a ksp pair. Slot swizzle s^(row&7) (full 8-spread).
// Fallback: round-1 fused kernel (proven, bf16).

typedef __bf16 bf16x8 __attribute__((ext_vector_type(8)));
typedef __bf16 bf16x4 __attribute__((ext_vector_type(4)));
typedef float f32x4 __attribute__((ext_vector_type(4)));
typedef long lx2 __attribute__((ext_vector_type(2)));

#define N_ROWS 100352
#define M_CENT 2048
#define D_K 1024

// fp8 fast-path geometry
#define BM4 128
#define BN4 128
#define BK4 128
#define NT4 (D_K / BK4)              // 8 K-tiles
#define NCT4 (M_CENT / BN4)          // 16 col tiles
#define NBLK4 ((N_ROWS / BM4) * NCT4)  // 12544
#define BPX4 (NBLK4 / 8)             // 1568 per XCD

// fallback geometry (round-1, unchanged)
#define TM 128
#define TN 128
#define BK 64
#define NT_TILES (M_CENT / TN)  // 16
#define KT_STEPS (D_K / BK)     // 16

#define AS1 __attribute__((address_space(1)))
#define AS3 __attribute__((address_space(3)))

#define WAITVM(N) asm volatile("s_waitcnt vmcnt(" #N ")" ::: "memory")
#define LGKM0 asm volatile("s_waitcnt lgkmcnt(0)" ::: "memory")
#define FENCE asm volatile("" ::: "memory")

// ---- prep: fp32 [rows][1024] -> packed fp8 row + per-row squared norm ----
// Packed byte position within row: seg(=K-tile)*128 + (ksp*4+g)*16 + h*8 + j
// where k = 32*(2*ksp+h) + 8*g + j.
__global__ __launch_bounds__(256) void rowsq_fp8pack(const float* __restrict__ src,
                                                     unsigned char* __restrict__ dst,
                                                     float* __restrict__ sq) {
  const int m = blockIdx.x;   // row
  const int t = threadIdx.x;  // 256 threads * 4 floats = 1024
  const float4 v = *reinterpret_cast<const float4*>(src + (size_t)m * D_K + t * 4);
  int pk = __builtin_amdgcn_cvt_pk_fp8_f32(v.x, v.y, 0, false);
  pk = __builtin_amdgcn_cvt_pk_fp8_f32(v.z, v.w, pk, true);
  const int k = t * 4;
  const int seg = k >> 7;
  const int ksi = (k >> 5) & 3;
  const int g = (k >> 3) & 3;
  const int j = k & 7;  // 0 or 4
  const int p = seg * 128 + (((ksi >> 1) * 4 + g) << 4) + (ksi & 1) * 8 + j;
  *reinterpret_cast<unsigned int*>(dst + (size_t)m * D_K + p) = (unsigned int)pk;
  float ss = v.x * v.x + v.y * v.y + v.z * v.z + v.w * v.w;
  ss += __shfl_xor(ss, 1);
  ss += __shfl_xor(ss, 2);
  ss += __shfl_xor(ss, 4);
  ss += __shfl_xor(ss, 8);
  ss += __shfl_xor(ss, 16);
  ss += __shfl_xor(ss, 32);
  __shared__ float ws4[4];
  const int w = t >> 6, l = t & 63;
  if (l == 0) ws4[w] = ss;
  __syncthreads();
  if (t == 0) sq[m] = ws4[0] + ws4[1] + ws4[2] + ws4[3];
}

// ---- fast path: fp8 128x128 tile, BK=128, dbuf, counted vmcnt ----
// LDS buffer: A[128 rows][128 B] 16K | B[128][128 B] 16K; 2 buffers = 64 KB.
// Staging: 8 global_load_lds w=16 per thread per K-tile (A:4, B:4), linear
// dest, inverse-swizzled packed-global source.
// K-tile kt (buf = kt&1):
//   WAITVM(8)      -- my stage(kt) landed (stage(kt+1) in flight)
//   s_barrier (B1) -- ALL waves' stage(kt) landed          (read-safety)
//   16 ds_read_b128 + 64 MFMA, NO wall: compiler interleaves (lgkmcnt N)
//   LGKM0 (free: all reads consumed); s_barrier (B2)       (WAR-safety)
//   stage(kt+2 -> buf)  -- overwrite the buffer just read by all waves
__global__ __launch_bounds__(256, 2) void gemm_min_fp8(const unsigned char* __restrict__ e8,
                                                       const unsigned char* __restrict__ c8,
                                                       const float* __restrict__ csq,
                                                       float* __restrict__ pmin) {
  __shared__ __align__(16) char lds[2 * 32768];
  __shared__ float rowmin2[2][BM4];

  const int t = threadIdx.x;
  const int w = t >> 6;
  const int l = t & 63;
  const int wr = w >> 1, wc = w & 1;  // 2x2 wave grid, 64x64 tiles
  const int g = l >> 4, lr = l & 15;

  // XCD swizzle: XCD k owns swz in [1568k,1568k+1568) = rp in [98k,98k+98)
  // x all 16 ct. c8 (2 MB) L2-resident; A panel (128 KB) reused 16x L2-hot.
  const int b = blockIdx.x;
  const int swz = (b & 7) * BPX4 + (b >> 3);
  const int rp = swz >> 4, ct = swz & 15;
  const long row0 = (long)rp * BM4;
  const int col0 = ct * BN4;

  // staging: dest linear d = i*4096 + t*16 -> row = i*32 + (t>>3), slot = t&7
  // (row&7 i-invariant). source = row*1024 + kt*128 + ((slot^(row&7))<<4).
  const int trow = t >> 3, tsl = t & 7;
  const int ssw = (tsl ^ (trow & 7)) << 4;
  const unsigned char* srcA0 = e8 + (row0 + trow) * (size_t)D_K + ssw;
  const unsigned char* srcB0 = c8 + (size_t)(col0 + trow) * D_K + ssw;
  const int dst0 = t * 16;

  f32x4 acc[4][4];
#pragma unroll
  for (int m = 0; m < 4; ++m)
#pragma unroll
    for (int n = 0; n < 4; ++n) acc[m][n] = (f32x4){0.f, 0.f, 0.f, 0.f};

  // loop-invariant swizzled read offsets: frag (m|n, ksp) slot = ksp*4+g
  int offA[4][2], offB[4][2];
#pragma unroll
  for (int m = 0; m < 4; ++m) {
    const int row = wr * 64 + m * 16 + lr;
#pragma unroll
    for (int ksp = 0; ksp < 2; ++ksp)
      offA[m][ksp] = row * 128 + (((ksp * 4 + g) ^ (row & 7)) << 4);
  }
#pragma unroll
  for (int n = 0; n < 4; ++n) {
    const int col = wc * 64 + n * 16 + lr;
#pragma unroll
    for (int ksp = 0; ksp < 2; ++ksp)
      offB[n][ksp] = 16384 + col * 128 + (((ksp * 4 + g) ^ (col & 7)) << 4);
  }

  lx2 af[4][2], bfr[4][2];

  auto stage = [&](int kt, int buf) {
    char* base = lds + buf * 32768;
    const size_t ko = (size_t)kt * BK4;
#pragma unroll
    for (int i = 0; i < 4; ++i)
      __builtin_amdgcn_global_load_lds(
          (const AS1 unsigned int*)(const void*)(srcA0 + (size_t)i * 32 * D_K + ko),
          (AS3 unsigned int*)(void*)(base + i * 4096 + dst0), 16, 0, 0);
#pragma unroll
    for (int i = 0; i < 4; ++i)
      __builtin_amdgcn_global_load_lds(
          (const AS1 unsigned int*)(const void*)(srcB0 + (size_t)i * 32 * D_K + ko),
          (AS3 unsigned int*)(void*)(base + 16384 + i * 4096 + dst0), 16, 0, 0);
  };

  auto readfrags = [&](int buf) {
    const char* base = lds + buf * 32768;
#pragma unroll
    for (int m = 0; m < 4; ++m)
#pragma unroll
      for (int ksp = 0; ksp < 2; ++ksp)
        af[m][ksp] = *reinterpret_cast<const lx2*>(base + offA[m][ksp]);
#pragma unroll
    for (int n = 0; n < 4; ++n)
#pragma unroll
      for (int ksp = 0; ksp < 2; ++ksp)
        bfr[n][ksp] = *reinterpret_cast<const lx2*>(base + offB[n][ksp]);
  };

  auto domfma = [&]() {
    __builtin_amdgcn_s_setprio(1);
#pragma unroll
    for (int ksp = 0; ksp < 2; ++ksp)
#pragma unroll
      for (int m = 0; m < 4; ++m)
#pragma unroll
        for (int n = 0; n < 4; ++n) {
          acc[m][n] = __builtin_amdgcn_mfma_f32_16x16x32_fp8_fp8(
              af[m][ksp][0], bfr[n][ksp][0], acc[m][n], 0, 0, 0);
          acc[m][n] = __builtin_amdgcn_mfma_f32_16x16x32_fp8_fp8(
              af[m][ksp][1], bfr[n][ksp][1], acc[m][n], 0, 0, 0);
        }
    __builtin_amdgcn_s_setprio(0);
  };

  stage(0, 0);
  stage(1, 1);
#pragma unroll
  for (int kt = 0; kt < NT4; ++kt) {
    const int buf = kt & 1;
    if (kt < NT4 - 1) {
      WAITVM(8);  // stage(kt) landed; stage(kt+1) stays in flight
    } else {
      WAITVM(0);  // last tile: only stage(7) in flight
    }
    FENCE;
    __builtin_amdgcn_s_barrier();  // B1: tile kt fully landed (all waves)
    FENCE;
    readfrags(buf);
    domfma();  // compiler interleaves ds_read/MFMA with fine lgkmcnt
    if (kt < NT4 - 2) {
      LGKM0;  // free: all reads already consumed by MFMA waits
      FENCE;
      __builtin_amdgcn_s_barrier();  // B2: all waves' reads of buf done
      FENCE;
      stage(kt + 2, buf);  // overwrite just-read buffer
    }
  }

  // --- partial min over this block's 128 cols: val = ||c||^2 - 2*dot ---
  float runmin[4][4];
#pragma unroll
  for (int m = 0; m < 4; ++m)
#pragma unroll
    for (int r = 0; r < 4; ++r) runmin[m][r] = 3.0e38f;
#pragma unroll
  for (int n = 0; n < 4; ++n) {
    const float cs = csq[col0 + wc * 64 + n * 16 + lr];
#pragma unroll
    for (int m = 0; m < 4; ++m)
#pragma unroll
      for (int r = 0; r < 4; ++r)
        runmin[m][r] = fminf(runmin[m][r], cs - 2.0f * acc[m][n][r]);
  }
#pragma unroll
  for (int m = 0; m < 4; ++m)
#pragma unroll
    for (int r = 0; r < 4; ++r) {
      float v = runmin[m][r];
      v = fminf(v, __shfl_xor(v, 1));
      v = fminf(v, __shfl_xor(v, 2));
      v = fminf(v, __shfl_xor(v, 4));
      v = fminf(v, __shfl_xor(v, 8));
      runmin[m][r] = v;
    }
  if (lr == 0) {
#pragma unroll
    for (int m = 0; m < 4; ++m)
#pragma unroll
      for (int r = 0; r < 4; ++r)
        rowmin2[wc][wr * 64 + m * 16 + g * 4 + r] = runmin[m][r];
  }
  __syncthreads();
  if (t < BM4) {
    pmin[(row0 + t) * NCT4 + ct] = fminf(rowmin2[0][t], rowmin2[1][t]);
  }
}

// ---- final: 16-way min + sqrt ----
__global__ __launch_bounds__(256) void final_min(const float* __restrict__ esq,
                                                 const float* __restrict__ pmin,
                                                 float* __restrict__ out) {
  const int r = blockIdx.x * 256 + threadIdx.x;
  const float4* p = reinterpret_cast<const float4*>(pmin + (size_t)r * 16);
  float4 a = p[0], b = p[1], c = p[2], d = p[3];
  float m = fminf(fminf(fminf(a.x, a.y), fminf(a.z, a.w)),
                  fminf(fminf(b.x, b.y), fminf(b.z, b.w)));
  m = fminf(m, fminf(fminf(fminf(c.x, c.y), fminf(c.z, c.w)),
                     fminf(fminf(d.x, d.y), fminf(d.z, d.w))));
  out[r] = sqrtf(fmaxf(esq[r] + m, 0.f));
}

// ---- bf16 prep (fallback path) ----
__global__ __launch_bounds__(256) void rowsq_bf16(const float* __restrict__ src,
                                                  __bf16* __restrict__ dst,
                                                  float* __restrict__ sq) {
  const int m = blockIdx.x;
  const int t = threadIdx.x;
  const float4 v = *reinterpret_cast<const float4*>(src + (size_t)m * D_K + t * 4);
  bf16x4 o = {(__bf16)v.x, (__bf16)v.y, (__bf16)v.z, (__bf16)v.w};
  *reinterpret_cast<bf16x4*>(dst + (size_t)m * D_K + t * 4) = o;
  float ss = v.x * v.x + v.y * v.y + v.z * v.z + v.w * v.w;
  ss += __shfl_xor(ss, 1);
  ss += __shfl_xor(ss, 2);
  ss += __shfl_xor(ss, 4);
  ss += __shfl_xor(ss, 8);
  ss += __shfl_xor(ss, 16);
  ss += __shfl_xor(ss, 32);
  __shared__ float ws4[4];
  const int w = t >> 6, l = t & 63;
  if (l == 0) ws4[w] = ss;
  __syncthreads();
  if (t == 0) sq[m] = ws4[0] + ws4[1] + ws4[2] + ws4[3];
}

// =================== round-1 fallback (proven) ===================
template <bool WS>
__global__ __launch_bounds__(256, 2) void fused_min(const float* __restrict__ embeds,
                                                    const float* __restrict__ centf,
                                                    const __bf16* __restrict__ cbf,
                                                    const float* __restrict__ csq,
                                                    float* __restrict__ out) {
  __shared__ __align__(16) char Ab[TM * 128];
  __shared__ __align__(16) char Bb[TN * 128];
  __shared__ float rowmin2[2][TM];
  __shared__ float sqrow[TM];
  __shared__ float colsq[TN];

  const int t = threadIdx.x;
  const int w = t >> 6;
  const int l = t & 63;
  const int wr = w >> 1, wc = w & 1;
  const int g = l >> 4, lr = l & 15;
  const long row0 = (long)blockIdx.x * TM;

  float runmin[4][4];
#pragma unroll
  for (int m = 0; m < 4; ++m)
#pragma unroll
    for (int r = 0; r < 4; ++r) runmin[m][r] = 3.0e38f;

  float sqpart[8];
#pragma unroll
  for (int c = 0; c < 8; ++c) sqpart[c] = 0.f;

  for (int nt = 0; nt < NT_TILES; ++nt) {
    const int col0 = nt * TN;
    f32x4 acc[4][4];
#pragma unroll
    for (int m = 0; m < 4; ++m)
#pragma unroll
      for (int n = 0; n < 4; ++n) acc[m][n] = (f32x4){0.f, 0.f, 0.f, 0.f};

    float cpart[8];
    if constexpr (!WS) {
#pragma unroll
      for (int c = 0; c < 8; ++c) cpart[c] = 0.f;
    }

    for (int kt = 0; kt < KT_STEPS; ++kt) {
      __syncthreads();
      if constexpr (WS) {
#pragma unroll
        for (int i = 0; i < 4; ++i) {
          const int s = (w * 4 + i) * 64 + l;
          const int col = s >> 3, sl = s & 7;
          const __bf16* src =
              cbf + (size_t)(col0 + col) * D_K + kt * BK + ((sl ^ (col & 7)) << 3);
          __builtin_amdgcn_global_load_lds(
              (const AS1 unsigned int*)(const void*)src,
              (AS3 unsigned int*)(void*)(Bb + (w * 4 + i) * 1024), 16, 0, 0);
        }
      } else {
#pragma unroll
        for (int c = 0; c < 8; ++c) {
          const int f = c * 256 + t;
          const int col = f >> 4, kq = f & 15;
          const float4 v = *reinterpret_cast<const float4*>(
              centf + (size_t)(col0 + col) * D_K + kt * BK + kq * 4);
          cpart[c] += v.x * v.x + v.y * v.y + v.z * v.z + v.w * v.w;
          bf16x4 o = {(__bf16)v.x, (__bf16)v.y, (__bf16)v.z, (__bf16)v.w};
          const int slot = kq >> 1;
          *reinterpret_cast<bf16x4*>(Bb + col * 128 + ((slot ^ (col & 7)) << 4) +
                                     (kq & 1) * 8) = o;
        }
      }
#pragma unroll
      for (int c = 0; c < 8; ++c) {
        const int f = c * 256 + t;
        const int row = f >> 4, kq = f & 15;
        const float4 v = *reinterpret_cast<const float4*>(
            embeds + (row0 + row) * (long)D_K + kt * BK + kq * 4);
        if (nt == 0) sqpart[c] += v.x * v.x + v.y * v.y + v.z * v.z + v.w * v.w;
        bf16x4 o = {(__bf16)v.x, (__bf16)v.y, (__bf16)v.z, (__bf16)v.w};
        const int slot = kq >> 1;
        *reinterpret_cast<bf16x4*>(Ab + row * 128 + ((slot ^ (row & 7)) << 4) +
                                   (kq & 1) * 8) = o;
      }
      __syncthreads();
#pragma unroll
      for (int ks = 0; ks < 2; ++ks) {
        bf16x8 af[4], bfr[4];
#pragma unroll
        for (int m = 0; m < 4; ++m) {
          const int row = wr * 64 + m * 16 + lr;
          const int slot = ks * 4 + g;
          af[m] = *reinterpret_cast<const bf16x8*>(Ab + row * 128 +
                                                   ((slot ^ (row & 7)) << 4));
        }
#pragma unroll
        for (int n = 0; n < 4; ++n) {
          const int col = wc * 64 + n * 16 + lr;
          const int slot = ks * 4 + g;
          bfr[n] = *reinterpret_cast<const bf16x8*>(Bb + col * 128 +
                                                    ((slot ^ (col & 7)) << 4));
        }
#pragma unroll
        for (int m = 0; m < 4; ++m)
#pragma unroll
          for (int n = 0; n < 4; ++n)
            acc[m][n] =
                __builtin_amdgcn_mfma_f32_16x16x32_bf16(af[m], bfr[n], acc[m][n], 0, 0, 0);
      }
    }

    if (nt == 0) {
#pragma unroll
      for (int c = 0; c < 8; ++c) {
        float ss = sqpart[c];
        ss += __shfl_xor(ss, 1);
        ss += __shfl_xor(ss, 2);
        ss += __shfl_xor(ss, 4);
        ss += __shfl_xor(ss, 8);
        if (lr == 0) sqrow[c * 16 + (w * 4 + g)] = ss;
      }
    }
    if constexpr (!WS) {
#pragma unroll
      for (int c = 0; c < 8; ++c) {
        float ss = cpart[c];
        ss += __shfl_xor(ss, 1);
        ss += __shfl_xor(ss, 2);
        ss += __shfl_xor(ss, 4);
        ss += __shfl_xor(ss, 8);
        if (lr == 0) colsq[c * 16 + (w * 4 + g)] = ss;
      }
      __syncthreads();
    }

#pragma unroll
    for (int n = 0; n < 4; ++n) {
      float cs;
      if constexpr (WS)
        cs = csq[col0 + wc * 64 + n * 16 + lr];
      else
        cs = colsq[wc * 64 + n * 16 + lr];
#pragma unroll
      for (int m = 0; m < 4; ++m)
#pragma unroll
        for (int r = 0; r < 4; ++r)
          runmin[m][r] = fminf(runmin[m][r], cs - 2.0f * acc[m][n][r]);
    }
  }

#pragma unroll
  for (int m = 0; m < 4; ++m)
#pragma unroll
    for (int r = 0; r < 4; ++r) {
      float v = runmin[m][r];
      v = fminf(v, __shfl_xor(v, 1));
      v = fminf(v, __shfl_xor(v, 2));
      v = fminf(v, __shfl_xor(v, 4));
      v = fminf(v, __shfl_xor(v, 8));
      runmin[m][r] = v;
    }
  if (lr == 0) {
#pragma unroll
    for (int m = 0; m < 4; ++m)
#pragma unroll
      for (int r = 0; r < 4; ++r)
        rowmin2[wc][wr * 64 + m * 16 + g * 4 + r] = runmin[m][r];
  }
  __syncthreads();
  if (t < TM) {
    const float v = fminf(rowmin2[0][t], rowmin2[1][t]);
    out[row0 + t] = sqrtf(fmaxf(sqrow[t] + v, 0.f));
  }
}

extern "C" void kernel_launch(void* const* d_in, const int* in_sizes, int n_in,
                              void* d_out, int out_size, void* d_ws, size_t ws_size,
                              hipStream_t stream) {
  const float* embeds = (const float*)d_in[0];
  const float* cent = (const float*)d_in[1];
  float* out = (float*)d_out;

  // ws layout for the fp8 fast path (~112 MiB)
  const size_t off_c8 = 0;
  const size_t off_csq = off_c8 + (size_t)M_CENT * D_K;             // 2 MiB
  const size_t off_e8 = off_csq + (size_t)M_CENT * 4;               // +8 KiB
  const size_t off_esq = off_e8 + (size_t)N_ROWS * D_K;             // +98 MiB
  const size_t off_pmin = off_esq + (size_t)N_ROWS * 4;             // +392 KiB
  const size_t need_full = off_pmin + (size_t)N_ROWS * NCT4 * 4;    // +6.1 MiB
  const size_t need_small = (size_t)M_CENT * D_K * 2 + (size_t)M_CENT * 4;

  if (ws_size >= need_full) {
    unsigned char* c8 = (unsigned char*)d_ws + off_c8;
    float* csq = (float*)((char*)d_ws + off_csq);
    unsigned char* e8 = (unsigned char*)d_ws + off_e8;
    float* esq = (float*)((char*)d_ws + off_esq);
    float* pmin = (float*)((char*)d_ws + off_pmin);
    rowsq_fp8pack<<<M_CENT, 256, 0, stream>>>(cent, c8, csq);
    rowsq_fp8pack<<<N_ROWS, 256, 0, stream>>>(embeds, e8, esq);
    gemm_min_fp8<<<NBLK4, 256, 0, stream>>>(e8, c8, csq, pmin);
    final_min<<<N_ROWS / 256, 256, 0, stream>>>(esq, pmin, out);
  } else if (ws_size >= need_small) {
    __bf16* cbf = (__bf16*)d_ws;
    float* csq = (float*)((char*)d_ws + (size_t)M_CENT * D_K * 2);
    rowsq_bf16<<<M_CENT, 256, 0, stream>>>(cent, cbf, csq);
    fused_min<true><<<N_ROWS / TM, 256, 0, stream>>>(embeds, cent, cbf, csq, out);
  } else {
    fused_min<false><<<N_ROWS / TM, 256, 0, stream>>>(embeds, cent, nullptr, nullptr, out);
  }
}

// Round 7
// 398.037 us; speedup vs baseline: 1.0361x; 1.0361x over previous
//
#include <hip/hip_runtime.h>
#include <hip/hip_bf16.h>

// CentroidsFlowAD: out[row] = sqrt(max(||e||^2 + min_col(||c||^2 - 2 e.c), 0))
// rows = 32*3136 = 100352, cols = 2048 centroids, K = 1024.
//
// Fast path (needs ~112 MiB ws), fp8 e4m3 cross-term (row norms exact fp32):
//   1. rowsq_fp8pack on centroids -> c8 (packed fp8) + csq
//   2. rowsq_fp8pack on embeds    -> e8 (packed fp8) + esq
//   3. gemm_min_fp8: 128x128 tile, BK=128, 4 waves (64x64), double-buffered
//      LDS 64 KiB -> 2 blocks/CU, counted vmcnt(8).
//      R7: NO s_setprio. Theory: setprio(1) around the MFMA cluster starved
//      the co-resident block's wave (2 waves/SIMD) of ds_read issue slots,
//      serializing read-phase and MFMA-phase across blocks (the invariant
//      ~50% wall of R0/R2/R5/R6). T5 is documented null-to-NEGATIVE on
//      2-phase GEMM (m190); it was carried here unexamined.
//   4. final_min: 16-way min + sqrt
// fp8 K-packed row layout (128B per K-tile of 128): 16B slot s=ksp*4+g holds
// k = {32*(2ksp)+8g..+7 | 32*(2ksp+1)+8g..+7} -> lane (g,lr) b128 = both
// MFMA operands of a ksp pair. Slot swizzle s^(row&7) (full 8-spread).
// Fallback: round-1 fused kernel (proven, bf16).

typedef __bf16 bf16x8 __attribute__((ext_vector_type(8)));
typedef __bf16 bf16x4 __attribute__((ext_vector_type(4)));
typedef float f32x4 __attribute__((ext_vector_type(4)));
typedef long lx2 __attribute__((ext_vector_type(2)));

#define N_ROWS 100352
#define M_CENT 2048
#define D_K 1024

// fp8 fast-path geometry
#define BM4 128
#define BN4 128
#define BK4 128
#define NT4 (D_K / BK4)              // 8 K-tiles
#define NCT4 (M_CENT / BN4)          // 16 col tiles
#define NBLK4 ((N_ROWS / BM4) * NCT4)  // 12544
#define BPX4 (NBLK4 / 8)             // 1568 per XCD

// fallback geometry (round-1, unchanged)
#define TM 128
#define TN 128
#define BK 64
#define NT_TILES (M_CENT / TN)  // 16
#define KT_STEPS (D_K / BK)     // 16

#define AS1 __attribute__((address_space(1)))
#define AS3 __attribute__((address_space(3)))

#define WAITVM(N) asm volatile("s_waitcnt vmcnt(" #N ")" ::: "memory")
#define LGKM0 asm volatile("s_waitcnt lgkmcnt(0)" ::: "memory")
#define FENCE asm volatile("" ::: "memory")

// ---- prep: fp32 [rows][1024] -> packed fp8 row + per-row squared norm ----
// Packed byte position within row: seg(=K-tile)*128 + (ksp*4+g)*16 + h*8 + j
// where k = 32*(2*ksp+h) + 8*g + j.
__global__ __launch_bounds__(256) void rowsq_fp8pack(const float* __restrict__ src,
                                                     unsigned char* __restrict__ dst,
                                                     float* __restrict__ sq) {
  const int m = blockIdx.x;   // row
  const int t = threadIdx.x;  // 256 threads * 4 floats = 1024
  const float4 v = *reinterpret_cast<const float4*>(src + (size_t)m * D_K + t * 4);
  int pk = __builtin_amdgcn_cvt_pk_fp8_f32(v.x, v.y, 0, false);
  pk = __builtin_amdgcn_cvt_pk_fp8_f32(v.z, v.w, pk, true);
  const int k = t * 4;
  const int seg = k >> 7;
  const int ksi = (k >> 5) & 3;
  const int g = (k >> 3) & 3;
  const int j = k & 7;  // 0 or 4
  const int p = seg * 128 + (((ksi >> 1) * 4 + g) << 4) + (ksi & 1) * 8 + j;
  *reinterpret_cast<unsigned int*>(dst + (size_t)m * D_K + p) = (unsigned int)pk;
  float ss = v.x * v.x + v.y * v.y + v.z * v.z + v.w * v.w;
  ss += __shfl_xor(ss, 1);
  ss += __shfl_xor(ss, 2);
  ss += __shfl_xor(ss, 4);
  ss += __shfl_xor(ss, 8);
  ss += __shfl_xor(ss, 16);
  ss += __shfl_xor(ss, 32);
  __shared__ float ws4[4];
  const int w = t >> 6, l = t & 63;
  if (l == 0) ws4[w] = ss;
  __syncthreads();
  if (t == 0) sq[m] = ws4[0] + ws4[1] + ws4[2] + ws4[3];
}

// ---- fast path: fp8 128x128 tile, BK=128, dbuf, counted vmcnt ----
// LDS buffer: A[128 rows][128 B] 16K | B[128][128 B] 16K; 2 buffers = 64 KB.
// Staging: 8 global_load_lds w=16 per thread per K-tile (A:4, B:4), linear
// dest, inverse-swizzled packed-global source.
// K-tile kt (buf = kt&1):
//   WAITVM(8)      -- my stage(kt) landed (stage(kt+1) in flight)
//   s_barrier (B1) -- ALL waves' stage(kt) landed          (read-safety)
//   16 ds_read_b128 + 64 MFMA (compiler interleaves, fine lgkmcnt; no
//     setprio -> co-resident block's waves keep issuing their reads/stages)
//   LGKM0; s_barrier (B2)                                  (WAR-safety)
//   stage(kt+2 -> buf)  -- overwrite the buffer just read by all waves
__global__ __launch_bounds__(256, 2) void gemm_min_fp8(const unsigned char* __restrict__ e8,
                                                       const unsigned char* __restrict__ c8,
                                                       const float* __restrict__ csq,
                                                       float* __restrict__ pmin) {
  __shared__ __align__(16) char lds[2 * 32768];
  __shared__ float rowmin2[2][BM4];

  const int t = threadIdx.x;
  const int w = t >> 6;
  const int l = t & 63;
  const int wr = w >> 1, wc = w & 1;  // 2x2 wave grid, 64x64 tiles
  const int g = l >> 4, lr = l & 15;

  // XCD swizzle: XCD k owns swz in [1568k,1568k+1568) = rp in [98k,98k+98)
  // x all 16 ct. c8 (2 MB) L2-resident; A panel (128 KB) reused 16x L2-hot.
  const int b = blockIdx.x;
  const int swz = (b & 7) * BPX4 + (b >> 3);
  const int rp = swz >> 4, ct = swz & 15;
  const long row0 = (long)rp * BM4;
  const int col0 = ct * BN4;

  // staging: dest linear d = i*4096 + t*16 -> row = i*32 + (t>>3), slot = t&7
  // (row&7 i-invariant). source = row*1024 + kt*128 + ((slot^(row&7))<<4).
  const int trow = t >> 3, tsl = t & 7;
  const int ssw = (tsl ^ (trow & 7)) << 4;
  const unsigned char* srcA0 = e8 + (row0 + trow) * (size_t)D_K + ssw;
  const unsigned char* srcB0 = c8 + (size_t)(col0 + trow) * D_K + ssw;
  const int dst0 = t * 16;

  f32x4 acc[4][4];
#pragma unroll
  for (int m = 0; m < 4; ++m)
#pragma unroll
    for (int n = 0; n < 4; ++n) acc[m][n] = (f32x4){0.f, 0.f, 0.f, 0.f};

  // loop-invariant swizzled read offsets: frag (m|n, ksp) slot = ksp*4+g
  int offA[4][2], offB[4][2];
#pragma unroll
  for (int m = 0; m < 4; ++m) {
    const int row = wr * 64 + m * 16 + lr;
#pragma unroll
    for (int ksp = 0; ksp < 2; ++ksp)
      offA[m][ksp] = row * 128 + (((ksp * 4 + g) ^ (row & 7)) << 4);
  }
#pragma unroll
  for (int n = 0; n < 4; ++n) {
    const int col = wc * 64 + n * 16 + lr;
#pragma unroll
    for (int ksp = 0; ksp < 2; ++ksp)
      offB[n][ksp] = 16384 + col * 128 + (((ksp * 4 + g) ^ (col & 7)) << 4);
  }

  lx2 af[4][2], bfr[4][2];

  auto stage = [&](int kt, int buf) {
    char* base = lds + buf * 32768;
    const size_t ko = (size_t)kt * BK4;
#pragma unroll
    for (int i = 0; i < 4; ++i)
      __builtin_amdgcn_global_load_lds(
          (const AS1 unsigned int*)(const void*)(srcA0 + (size_t)i * 32 * D_K + ko),
          (AS3 unsigned int*)(void*)(base + i * 4096 + dst0), 16, 0, 0);
#pragma unroll
    for (int i = 0; i < 4; ++i)
      __builtin_amdgcn_global_load_lds(
          (const AS1 unsigned int*)(const void*)(srcB0 + (size_t)i * 32 * D_K + ko),
          (AS3 unsigned int*)(void*)(base + 16384 + i * 4096 + dst0), 16, 0, 0);
  };

  auto readfrags = [&](int buf) {
    const char* base = lds + buf * 32768;
#pragma unroll
    for (int m = 0; m < 4; ++m)
#pragma unroll
      for (int ksp = 0; ksp < 2; ++ksp)
        af[m][ksp] = *reinterpret_cast<const lx2*>(base + offA[m][ksp]);
#pragma unroll
    for (int n = 0; n < 4; ++n)
#pragma unroll
      for (int ksp = 0; ksp < 2; ++ksp)
        bfr[n][ksp] = *reinterpret_cast<const lx2*>(base + offB[n][ksp]);
  };

  auto domfma = [&]() {
#pragma unroll
    for (int ksp = 0; ksp < 2; ++ksp)
#pragma unroll
      for (int m = 0; m < 4; ++m)
#pragma unroll
        for (int n = 0; n < 4; ++n) {
          acc[m][n] = __builtin_amdgcn_mfma_f32_16x16x32_fp8_fp8(
              af[m][ksp][0], bfr[n][ksp][0], acc[m][n], 0, 0, 0);
          acc[m][n] = __builtin_amdgcn_mfma_f32_16x16x32_fp8_fp8(
              af[m][ksp][1], bfr[n][ksp][1], acc[m][n], 0, 0, 0);
        }
  };

  stage(0, 0);
  stage(1, 1);
#pragma unroll
  for (int kt = 0; kt < NT4; ++kt) {
    const int buf = kt & 1;
    if (kt < NT4 - 1) {
      WAITVM(8);  // stage(kt) landed; stage(kt+1) stays in flight
    } else {
      WAITVM(0);  // last tile: only stage(7) in flight
    }
    FENCE;
    __builtin_amdgcn_s_barrier();  // B1: tile kt fully landed (all waves)
    FENCE;
    readfrags(buf);
    domfma();  // compiler interleaves ds_read/MFMA with fine lgkmcnt
    if (kt < NT4 - 2) {
      LGKM0;  // free: all reads already consumed by MFMA waits
      FENCE;
      __builtin_amdgcn_s_barrier();  // B2: all waves' reads of buf done
      FENCE;
      stage(kt + 2, buf);  // overwrite just-read buffer
    }
  }

  // --- partial min over this block's 128 cols: val = ||c||^2 - 2*dot ---
  float runmin[4][4];
#pragma unroll
  for (int m = 0; m < 4; ++m)
#pragma unroll
    for (int r = 0; r < 4; ++r) runmin[m][r] = 3.0e38f;
#pragma unroll
  for (int n = 0; n < 4; ++n) {
    const float cs = csq[col0 + wc * 64 + n * 16 + lr];
#pragma unroll
    for (int m = 0; m < 4; ++m)
#pragma unroll
      for (int r = 0; r < 4; ++r)
        runmin[m][r] = fminf(runmin[m][r], cs - 2.0f * acc[m][n][r]);
  }
#pragma unroll
  for (int m = 0; m < 4; ++m)
#pragma unroll
    for (int r = 0; r < 4; ++r) {
      float v = runmin[m][r];
      v = fminf(v, __shfl_xor(v, 1));
      v = fminf(v, __shfl_xor(v, 2));
      v = fminf(v, __shfl_xor(v, 4));
      v = fminf(v, __shfl_xor(v, 8));
      runmin[m][r] = v;
    }
  if (lr == 0) {
#pragma unroll
    for (int m = 0; m < 4; ++m)
#pragma unroll
      for (int r = 0; r < 4; ++r)
        rowmin2[wc][wr * 64 + m * 16 + g * 4 + r] = runmin[m][r];
  }
  __syncthreads();
  if (t < BM4) {
    pmin[(row0 + t) * NCT4 + ct] = fminf(rowmin2[0][t], rowmin2[1][t]);
  }
}

// ---- final: 16-way min + sqrt ----
__global__ __launch_bounds__(256) void final_min(const float* __restrict__ esq,
                                                 const float* __restrict__ pmin,
                                                 float* __restrict__ out) {
  const int r = blockIdx.x * 256 + threadIdx.x;
  const float4* p = reinterpret_cast<const float4*>(pmin + (size_t)r * 16);
  float4 a = p[0], b = p[1], c = p[2], d = p[3];
  float m = fminf(fminf(fminf(a.x, a.y), fminf(a.z, a.w)),
                  fminf(fminf(b.x, b.y), fminf(b.z, b.w)));
  m = fminf(m, fminf(fminf(fminf(c.x, c.y), fminf(c.z, c.w)),
                     fminf(fminf(d.x, d.y), fminf(d.z, d.w))));
  out[r] = sqrtf(fmaxf(esq[r] + m, 0.f));
}

// ---- bf16 prep (fallback path) ----
__global__ __launch_bounds__(256) void rowsq_bf16(const float* __restrict__ src,
                                                  __bf16* __restrict__ dst,
                                                  float* __restrict__ sq) {
  const int m = blockIdx.x;
  const int t = threadIdx.x;
  const float4 v = *reinterpret_cast<const float4*>(src + (size_t)m * D_K + t * 4);
  bf16x4 o = {(__bf16)v.x, (__bf16)v.y, (__bf16)v.z, (__bf16)v.w};
  *reinterpret_cast<bf16x4*>(dst + (size_t)m * D_K + t * 4) = o;
  float ss = v.x * v.x + v.y * v.y + v.z * v.z + v.w * v.w;
  ss += __shfl_xor(ss, 1);
  ss += __shfl_xor(ss, 2);
  ss += __shfl_xor(ss, 4);
  ss += __shfl_xor(ss, 8);
  ss += __shfl_xor(ss, 16);
  ss += __shfl_xor(ss, 32);
  __shared__ float ws4[4];
  const int w = t >> 6, l = t & 63;
  if (l == 0) ws4[w] = ss;
  __syncthreads();
  if (t == 0) sq[m] = ws4[0] + ws4[1] + ws4[2] + ws4[3];
}

// =================== round-1 fallback (proven) ===================
template <bool WS>
__global__ __launch_bounds__(256, 2) void fused_min(const float* __restrict__ embeds,
                                                    const float* __restrict__ centf,
                                                    const __bf16* __restrict__ cbf,
                                                    const float* __restrict__ csq,
                                                    float* __restrict__ out) {
  __shared__ __align__(16) char Ab[TM * 128];
  __shared__ __align__(16) char Bb[TN * 128];
  __shared__ float rowmin2[2][TM];
  __shared__ float sqrow[TM];
  __shared__ float colsq[TN];

  const int t = threadIdx.x;
  const int w = t >> 6;
  const int l = t & 63;
  const int wr = w >> 1, wc = w & 1;
  const int g = l >> 4, lr = l & 15;
  const long row0 = (long)blockIdx.x * TM;

  float runmin[4][4];
#pragma unroll
  for (int m = 0; m < 4; ++m)
#pragma unroll
    for (int r = 0; r < 4; ++r) runmin[m][r] = 3.0e38f;

  float sqpart[8];
#pragma unroll
  for (int c = 0; c < 8; ++c) sqpart[c] = 0.f;

  for (int nt = 0; nt < NT_TILES; ++nt) {
    const int col0 = nt * TN;
    f32x4 acc[4][4];
#pragma unroll
    for (int m = 0; m < 4; ++m)
#pragma unroll
      for (int n = 0; n < 4; ++n) acc[m][n] = (f32x4){0.f, 0.f, 0.f, 0.f};

    float cpart[8];
    if constexpr (!WS) {
#pragma unroll
      for (int c = 0; c < 8; ++c) cpart[c] = 0.f;
    }

    for (int kt = 0; kt < KT_STEPS; ++kt) {
      __syncthreads();
      if constexpr (WS) {
#pragma unroll
        for (int i = 0; i < 4; ++i) {
          const int s = (w * 4 + i) * 64 + l;
          const int col = s >> 3, sl = s & 7;
          const __bf16* src =
              cbf + (size_t)(col0 + col) * D_K + kt * BK + ((sl ^ (col & 7)) << 3);
          __builtin_amdgcn_global_load_lds(
              (const AS1 unsigned int*)(const void*)src,
              (AS3 unsigned int*)(void*)(Bb + (w * 4 + i) * 1024), 16, 0, 0);
        }
      } else {
#pragma unroll
        for (int c = 0; c < 8; ++c) {
          const int f = c * 256 + t;
          const int col = f >> 4, kq = f & 15;
          const float4 v = *reinterpret_cast<const float4*>(
              centf + (size_t)(col0 + col) * D_K + kt * BK + kq * 4);
          cpart[c] += v.x * v.x + v.y * v.y + v.z * v.z + v.w * v.w;
          bf16x4 o = {(__bf16)v.x, (__bf16)v.y, (__bf16)v.z, (__bf16)v.w};
          const int slot = kq >> 1;
          *reinterpret_cast<bf16x4*>(Bb + col * 128 + ((slot ^ (col & 7)) << 4) +
                                     (kq & 1) * 8) = o;
        }
      }
#pragma unroll
      for (int c = 0; c < 8; ++c) {
        const int f = c * 256 + t;
        const int row = f >> 4, kq = f & 15;
        const float4 v = *reinterpret_cast<const float4*>(
            embeds + (row0 + row) * (long)D_K + kt * BK + kq * 4);
        if (nt == 0) sqpart[c] += v.x * v.x + v.y * v.y + v.z * v.z + v.w * v.w;
        bf16x4 o = {(__bf16)v.x, (__bf16)v.y, (__bf16)v.z, (__bf16)v.w};
        const int slot = kq >> 1;
        *reinterpret_cast<bf16x4*>(Ab + row * 128 + ((slot ^ (row & 7)) << 4) +
                                   (kq & 1) * 8) = o;
      }
      __syncthreads();
#pragma unroll
      for (int ks = 0; ks < 2; ++ks) {
        bf16x8 af[4], bfr[4];
#pragma unroll
        for (int m = 0; m < 4; ++m) {
          const int row = wr * 64 + m * 16 + lr;
          const int slot = ks * 4 + g;
          af[m] = *reinterpret_cast<const bf16x8*>(Ab + row * 128 +
                                                   ((slot ^ (row & 7)) << 4));
        }
#pragma unroll
        for (int n = 0; n < 4; ++n) {
          const int col = wc * 64 + n * 16 + lr;
          const int slot = ks * 4 + g;
          bfr[n] = *reinterpret_cast<const bf16x8*>(Bb + col * 128 +
                                                    ((slot ^ (col & 7)) << 4));
        }
#pragma unroll
        for (int m = 0; m < 4; ++m)
#pragma unroll
          for (int n = 0; n < 4; ++n)
            acc[m][n] =
                __builtin_amdgcn_mfma_f32_16x16x32_bf16(af[m], bfr[n], acc[m][n], 0, 0, 0);
      }
    }

    if (nt == 0) {
#pragma unroll
      for (int c = 0; c < 8; ++c) {
        float ss = sqpart[c];
        ss += __shfl_xor(ss, 1);
        ss += __shfl_xor(ss, 2);
        ss += __shfl_xor(ss, 4);
        ss += __shfl_xor(ss, 8);
        if (lr == 0) sqrow[c * 16 + (w * 4 + g)] = ss;
      }
    }
    if constexpr (!WS) {
#pragma unroll
      for (int c = 0; c < 8; ++c) {
        float ss = cpart[c];
        ss += __shfl_xor(ss, 1);
        ss += __shfl_xor(ss, 2);
        ss += __shfl_xor(ss, 4);
        ss += __shfl_xor(ss, 8);
        if (lr == 0) colsq[c * 16 + (w * 4 + g)] = ss;
      }
      __syncthreads();
    }

#pragma unroll
    for (int n = 0; n < 4; ++n) {
      float cs;
      if constexpr (WS)
        cs = csq[col0 + wc * 64 + n * 16 + lr];
      else
        cs = colsq[wc * 64 + n * 16 + lr];
#pragma unroll
      for (int m = 0; m < 4; ++m)
#pragma unroll
        for (int r = 0; r < 4; ++r)
          runmin[m][r] = fminf(runmin[m][r], cs - 2.0f * acc[m][n][r]);
    }
  }

#pragma unroll
  for (int m = 0; m < 4; ++m)
#pragma unroll
    for (int r = 0; r < 4; ++r) {
      float v = runmin[m][r];
      v = fminf(v, __shfl_xor(v, 1));
      v = fminf(v, __shfl_xor(v, 2));
      v = fminf(v, __shfl_xor(v, 4));
      v = fminf(v, __shfl_xor(v, 8));
      runmin[m][r] = v;
    }
  if (lr == 0) {
#pragma unroll
    for (int m = 0; m < 4; ++m)
#pragma unroll
      for (int r = 0; r < 4; ++r)
        rowmin2[wc][wr * 64 + m * 16 + g * 4 + r] = runmin[m][r];
  }
  __syncthreads();
  if (t < TM) {
    const float v = fminf(rowmin2[0][t], rowmin2[1][t]);
    out[row0 + t] = sqrtf(fmaxf(sqrow[t] + v, 0.f));
  }
}

extern "C" void kernel_launch(void* const* d_in, const int* in_sizes, int n_in,
                              void* d_out, int out_size, void* d_ws, size_t ws_size,
                              hipStream_t stream) {
  const float* embeds = (const float*)d_in[0];
  const float* cent = (const float*)d_in[1];
  float* out = (float*)d_out;

  // ws layout for the fp8 fast path (~112 MiB)
  const size_t off_c8 = 0;
  const size_t off_csq = off_c8 + (size_t)M_CENT * D_K;             // 2 MiB
  const size_t off_e8 = off_csq + (size_t)M_CENT * 4;               // +8 KiB
  const size_t off_esq = off_e8 + (size_t)N_ROWS * D_K;             // +98 MiB
  const size_t off_pmin = off_esq + (size_t)N_ROWS * 4;             // +392 KiB
  const size_t need_full = off_pmin + (size_t)N_ROWS * NCT4 * 4;    // +6.1 MiB
  const size_t need_small = (size_t)M_CENT * D_K * 2 + (size_t)M_CENT * 4;

  if (ws_size >= need_full) {
    unsigned char* c8 = (unsigned char*)d_ws + off_c8;
    float* csq = (float*)((char*)d_ws + off_csq);
    unsigned char* e8 = (unsigned char*)d_ws + off_e8;
    float* esq = (float*)((char*)d_ws + off_esq);
    float* pmin = (float*)((char*)d_ws + off_pmin);
    rowsq_fp8pack<<<M_CENT, 256, 0, stream>>>(cent, c8, csq);
    rowsq_fp8pack<<<N_ROWS, 256, 0, stream>>>(embeds, e8, esq);
    gemm_min_fp8<<<NBLK4, 256, 0, stream>>>(e8, c8, csq, pmin);
    final_min<<<N_ROWS / 256, 256, 0, stream>>>(esq, pmin, out);
  } else if (ws_size >= need_small) {
    __bf16* cbf = (__bf16*)d_ws;
    float* csq = (float*)((char*)d_ws + (size_t)M_CENT * D_K * 2);
    rowsq_bf16<<<M_CENT, 256, 0, stream>>>(cent, cbf, csq);
    fused_min<true><<<N_ROWS / TM, 256, 0, stream>>>(embeds, cent, cbf, csq, out);
  } else {
    fused_min<false><<<N_ROWS / TM, 256, 0, stream>>>(embeds, cent, nullptr, nullptr, out);
  }
}

// Round 8
// 352.711 us; speedup vs baseline: 1.1692x; 1.1285x over previous
//
#include <hip/hip_runtime.h>
#include <hip/hip_bf16.h>

// CentroidsFlowAD: out[row] = sqrt(max(||e||^2 + min_col(||c||^2 - 2 e.c), 0))
// rows = 32*3136 = 100352, cols = 2048 centroids, K = 1024.
//
// Fast path (needs ~112 MiB ws), fp8 e4m3 cross-term (row norms exact fp32):
//   1. rowsq_fp8pack on centroids -> c8 (packed fp8) + csq
//   2. rowsq_fp8pack on embeds    -> e8 (packed fp8) + esq
//   3. gemm_min_fp8: 128x128 tile, BK=64, 4 waves (64x64), double-buffered
//      LDS 32 KiB -> 4 BLOCKS/CU (R8: was 2 at BK=128). Theory: 2 blocks/CU
//      phase-lock (both read together, both MFMA together -> LDS and MFMA
//      serialize, the 53% wall); 4 independent blocks/SIMD mix phases.
//      Counted vmcnt(4) (drains only at last tile), no setprio (R7: -3.5%).
//      Discipline: WAITVM -> B1 -> reads+MFMA -> LGKM0 -> B2 -> stage(kt+2).
//   4. final_min: 16-way min + sqrt
// fp8 K-packed row layout (64B per K-tile of 64): 16B slot g holds
// k = {32*0+8g..+7 | 32*1+8g..+7} (two 8B halves = the two MFMAs' operands).
// Byte pos: p = (k>>6)*64 + ((k>>3)&3)*16 + ((k>>5)&1)*8 + (k&7).
// Slot swizzle sl ^ ((row>>1)&3) (2-way residual on rows 8 apart = free).
// Fallback: round-1 fused kernel (proven, bf16).

typedef __bf16 bf16x8 __attribute__((ext_vector_type(8)));
typedef __bf16 bf16x4 __attribute__((ext_vector_type(4)));
typedef float f32x4 __attribute__((ext_vector_type(4)));
typedef long lx2 __attribute__((ext_vector_type(2)));

#define N_ROWS 100352
#define M_CENT 2048
#define D_K 1024

// fp8 fast-path geometry
#define BM4 128
#define BN4 128
#define BK4 64
#define NT4 (D_K / BK4)                // 16 K-tiles
#define NCT4 (M_CENT / BN4)            // 16 col tiles
#define NBLK4 ((N_ROWS / BM4) * NCT4)  // 12544
#define BPX4 (NBLK4 / 8)               // 1568 per XCD
#define BUF4 16384                     // A[128][64B] 8K | B[128][64B] 8K

// fallback geometry (round-1, unchanged)
#define TM 128
#define TN 128
#define BK 64
#define NT_TILES (M_CENT / TN)  // 16
#define KT_STEPS (D_K / BK)     // 16

#define AS1 __attribute__((address_space(1)))
#define AS3 __attribute__((address_space(3)))

#define WAITVM(N) asm volatile("s_waitcnt vmcnt(" #N ")" ::: "memory")
#define LGKM0 asm volatile("s_waitcnt lgkmcnt(0)" ::: "memory")
#define FENCE asm volatile("" ::: "memory")

// ---- prep: fp32 [rows][1024] -> packed fp8 row + per-row squared norm ----
// p(k) = (k>>6)*64 + ((k>>3)&3)*16 + ((k>>5)&1)*8 + (k&7)
__global__ __launch_bounds__(256) void rowsq_fp8pack(const float* __restrict__ src,
                                                     unsigned char* __restrict__ dst,
                                                     float* __restrict__ sq) {
  const int m = blockIdx.x;   // row
  const int t = threadIdx.x;  // 256 threads * 4 floats = 1024
  const float4 v = *reinterpret_cast<const float4*>(src + (size_t)m * D_K + t * 4);
  int pk = __builtin_amdgcn_cvt_pk_fp8_f32(v.x, v.y, 0, false);
  pk = __builtin_amdgcn_cvt_pk_fp8_f32(v.z, v.w, pk, true);
  const int k = t * 4;
  const int p = (k >> 6) * 64 + (((k >> 3) & 3) << 4) + ((k >> 5) & 1) * 8 + (k & 7);
  *reinterpret_cast<unsigned int*>(dst + (size_t)m * D_K + p) = (unsigned int)pk;
  float ss = v.x * v.x + v.y * v.y + v.z * v.z + v.w * v.w;
  ss += __shfl_xor(ss, 1);
  ss += __shfl_xor(ss, 2);
  ss += __shfl_xor(ss, 4);
  ss += __shfl_xor(ss, 8);
  ss += __shfl_xor(ss, 16);
  ss += __shfl_xor(ss, 32);
  __shared__ float ws4[4];
  const int w = t >> 6, l = t & 63;
  if (l == 0) ws4[w] = ss;
  __syncthreads();
  if (t == 0) sq[m] = ws4[0] + ws4[1] + ws4[2] + ws4[3];
}

// ---- fast path: fp8 128x128 tile, BK=64, dbuf, counted vmcnt, 4 blk/CU ----
// LDS buffer: A[128 rows][64 B] 8K | B[128][64 B] 8K; 2 buffers = 32 KB.
// Staging: 4 global_load_lds w=16 per thread per K-tile (A:2, B:2), linear
// dest, inverse-swizzled packed-global source.
// K-tile kt (buf = kt&1):
//   WAITVM(4)      -- my stage(kt) landed (stage(kt+1) in flight)
//   s_barrier (B1) -- ALL waves' stage(kt) landed          (read-safety)
//   8 ds_read_b128 + 32 MFMA (compiler interleaves with fine lgkmcnt)
//   LGKM0; s_barrier (B2)                                  (WAR-safety)
//   stage(kt+2 -> buf)  -- overwrite the buffer just read by all waves
__global__ __launch_bounds__(256, 4) void gemm_min_fp8(const unsigned char* __restrict__ e8,
                                                       const unsigned char* __restrict__ c8,
                                                       const float* __restrict__ csq,
                                                       float* __restrict__ pmin) {
  __shared__ __align__(16) char lds[2 * BUF4];
  __shared__ float rowmin2[2][BM4];

  const int t = threadIdx.x;
  const int w = t >> 6;
  const int l = t & 63;
  const int wr = w >> 1, wc = w & 1;  // 2x2 wave grid, 64x64 tiles
  const int g = l >> 4, lr = l & 15;

  // XCD swizzle: XCD k owns swz in [1568k,1568k+1568) = rp in [98k,98k+98)
  // x all 16 ct. c8 (2 MB) L2-resident; A panel (128 KB) reused 16x L2-hot.
  const int b = blockIdx.x;
  const int swz = (b & 7) * BPX4 + (b >> 3);
  const int rp = swz >> 4, ct = swz & 15;
  const long row0 = (long)rp * BM4;
  const int col0 = ct * BN4;

  // staging: slot S = i*256 + t -> row = i*64 + (t>>2), slot_pos = t&3;
  // (row>>1)&3 = (t>>3)&3 (i-invariant). src slot = slot_pos ^ swz(row).
  const int trow = t >> 2;
  const int ssw = ((t & 3) ^ ((t >> 3) & 3)) << 4;
  const unsigned char* srcA0 = e8 + (row0 + trow) * (size_t)D_K + ssw;
  const unsigned char* srcB0 = c8 + (size_t)(col0 + trow) * D_K + ssw;
  const int dst0 = t * 16;

  f32x4 acc[4][4];
#pragma unroll
  for (int m = 0; m < 4; ++m)
#pragma unroll
    for (int n = 0; n < 4; ++n) acc[m][n] = (f32x4){0.f, 0.f, 0.f, 0.f};

  // loop-invariant swizzled read offsets: frag slot = g (one lx2 per m|n)
  int offA[4], offB[4];
#pragma unroll
  for (int m = 0; m < 4; ++m) {
    const int row = wr * 64 + m * 16 + lr;
    offA[m] = row * 64 + ((g ^ ((row >> 1) & 3)) << 4);
  }
#pragma unroll
  for (int n = 0; n < 4; ++n) {
    const int col = wc * 64 + n * 16 + lr;
    offB[n] = 8192 + col * 64 + ((g ^ ((col >> 1) & 3)) << 4);
  }

  lx2 af[4], bfr[4];

  auto stage = [&](int kt, int buf) {
    char* base = lds + buf * BUF4;
    const size_t ko = (size_t)kt * BK4;
#pragma unroll
    for (int i = 0; i < 2; ++i)
      __builtin_amdgcn_global_load_lds(
          (const AS1 unsigned int*)(const void*)(srcA0 + (size_t)i * 64 * D_K + ko),
          (AS3 unsigned int*)(void*)(base + i * 4096 + dst0), 16, 0, 0);
#pragma unroll
    for (int i = 0; i < 2; ++i)
      __builtin_amdgcn_global_load_lds(
          (const AS1 unsigned int*)(const void*)(srcB0 + (size_t)i * 64 * D_K + ko),
          (AS3 unsigned int*)(void*)(base + 8192 + i * 4096 + dst0), 16, 0, 0);
  };

  auto readfrags = [&](int buf) {
    const char* base = lds + buf * BUF4;
#pragma unroll
    for (int m = 0; m < 4; ++m) af[m] = *reinterpret_cast<const lx2*>(base + offA[m]);
#pragma unroll
    for (int n = 0; n < 4; ++n) bfr[n] = *reinterpret_cast<const lx2*>(base + offB[n]);
  };

  auto domfma = [&]() {
#pragma unroll
    for (int m = 0; m < 4; ++m)
#pragma unroll
      for (int n = 0; n < 4; ++n) {
        acc[m][n] = __builtin_amdgcn_mfma_f32_16x16x32_fp8_fp8(af[m][0], bfr[n][0],
                                                               acc[m][n], 0, 0, 0);
        acc[m][n] = __builtin_amdgcn_mfma_f32_16x16x32_fp8_fp8(af[m][1], bfr[n][1],
                                                               acc[m][n], 0, 0, 0);
      }
  };

  stage(0, 0);
  stage(1, 1);
#pragma unroll
  for (int kt = 0; kt < NT4; ++kt) {
    const int buf = kt & 1;
    if (kt < NT4 - 1) {
      WAITVM(4);  // stage(kt) landed; stage(kt+1) stays in flight
    } else {
      WAITVM(0);  // last tile: only stage(15) in flight
    }
    FENCE;
    __builtin_amdgcn_s_barrier();  // B1: tile kt fully landed (all waves)
    FENCE;
    readfrags(buf);
    domfma();  // compiler interleaves ds_read/MFMA with fine lgkmcnt
    if (kt < NT4 - 2) {
      LGKM0;  // free: all reads already consumed by MFMA waits
      FENCE;
      __builtin_amdgcn_s_barrier();  // B2: all waves' reads of buf done
      FENCE;
      stage(kt + 2, buf);  // overwrite just-read buffer
    }
  }

  // --- partial min over this block's 128 cols: val = ||c||^2 - 2*dot ---
  float runmin[4][4];
#pragma unroll
  for (int m = 0; m < 4; ++m)
#pragma unroll
    for (int r = 0; r < 4; ++r) runmin[m][r] = 3.0e38f;
#pragma unroll
  for (int n = 0; n < 4; ++n) {
    const float cs = csq[col0 + wc * 64 + n * 16 + lr];
#pragma unroll
    for (int m = 0; m < 4; ++m)
#pragma unroll
      for (int r = 0; r < 4; ++r)
        runmin[m][r] = fminf(runmin[m][r], cs - 2.0f * acc[m][n][r]);
  }
#pragma unroll
  for (int m = 0; m < 4; ++m)
#pragma unroll
    for (int r = 0; r < 4; ++r) {
      float v = runmin[m][r];
      v = fminf(v, __shfl_xor(v, 1));
      v = fminf(v, __shfl_xor(v, 2));
      v = fminf(v, __shfl_xor(v, 4));
      v = fminf(v, __shfl_xor(v, 8));
      runmin[m][r] = v;
    }
  if (lr == 0) {
#pragma unroll
    for (int m = 0; m < 4; ++m)
#pragma unroll
      for (int r = 0; r < 4; ++r)
        rowmin2[wc][wr * 64 + m * 16 + g * 4 + r] = runmin[m][r];
  }
  __syncthreads();
  if (t < BM4) {
    pmin[(row0 + t) * NCT4 + ct] = fminf(rowmin2[0][t], rowmin2[1][t]);
  }
}

// ---- final: 16-way min + sqrt ----
__global__ __launch_bounds__(256) void final_min(const float* __restrict__ esq,
                                                 const float* __restrict__ pmin,
                                                 float* __restrict__ out) {
  const int r = blockIdx.x * 256 + threadIdx.x;
  const float4* p = reinterpret_cast<const float4*>(pmin + (size_t)r * 16);
  float4 a = p[0], b = p[1], c = p[2], d = p[3];
  float m = fminf(fminf(fminf(a.x, a.y), fminf(a.z, a.w)),
                  fminf(fminf(b.x, b.y), fminf(b.z, b.w)));
  m = fminf(m, fminf(fminf(fminf(c.x, c.y), fminf(c.z, c.w)),
                     fminf(fminf(d.x, d.y), fminf(d.z, d.w))));
  out[r] = sqrtf(fmaxf(esq[r] + m, 0.f));
}

// ---- bf16 prep (fallback path) ----
__global__ __launch_bounds__(256) void rowsq_bf16(const float* __restrict__ src,
                                                  __bf16* __restrict__ dst,
                                                  float* __restrict__ sq) {
  const int m = blockIdx.x;
  const int t = threadIdx.x;
  const float4 v = *reinterpret_cast<const float4*>(src + (size_t)m * D_K + t * 4);
  bf16x4 o = {(__bf16)v.x, (__bf16)v.y, (__bf16)v.z, (__bf16)v.w};
  *reinterpret_cast<bf16x4*>(dst + (size_t)m * D_K + t * 4) = o;
  float ss = v.x * v.x + v.y * v.y + v.z * v.z + v.w * v.w;
  ss += __shfl_xor(ss, 1);
  ss += __shfl_xor(ss, 2);
  ss += __shfl_xor(ss, 4);
  ss += __shfl_xor(ss, 8);
  ss += __shfl_xor(ss, 16);
  ss += __shfl_xor(ss, 32);
  __shared__ float ws4[4];
  const int w = t >> 6, l = t & 63;
  if (l == 0) ws4[w] = ss;
  __syncthreads();
  if (t == 0) sq[m] = ws4[0] + ws4[1] + ws4[2] + ws4[3];
}

// =================== round-1 fallback (proven) ===================
template <bool WS>
__global__ __launch_bounds__(256, 2) void fused_min(const float* __restrict__ embeds,
                                                    const float* __restrict__ centf,
                                                    const __bf16* __restrict__ cbf,
                                                    const float* __restrict__ csq,
                                                    float* __restrict__ out) {
  __shared__ __align__(16) char Ab[TM * 128];
  __shared__ __align__(16) char Bb[TN * 128];
  __shared__ float rowmin2[2][TM];
  __shared__ float sqrow[TM];
  __shared__ float colsq[TN];

  const int t = threadIdx.x;
  const int w = t >> 6;
  const int l = t & 63;
  const int wr = w >> 1, wc = w & 1;
  const int g = l >> 4, lr = l & 15;
  const long row0 = (long)blockIdx.x * TM;

  float runmin[4][4];
#pragma unroll
  for (int m = 0; m < 4; ++m)
#pragma unroll
    for (int r = 0; r < 4; ++r) runmin[m][r] = 3.0e38f;

  float sqpart[8];
#pragma unroll
  for (int c = 0; c < 8; ++c) sqpart[c] = 0.f;

  for (int nt = 0; nt < NT_TILES; ++nt) {
    const int col0 = nt * TN;
    f32x4 acc[4][4];
#pragma unroll
    for (int m = 0; m < 4; ++m)
#pragma unroll
      for (int n = 0; n < 4; ++n) acc[m][n] = (f32x4){0.f, 0.f, 0.f, 0.f};

    float cpart[8];
    if constexpr (!WS) {
#pragma unroll
      for (int c = 0; c < 8; ++c) cpart[c] = 0.f;
    }

    for (int kt = 0; kt < KT_STEPS; ++kt) {
      __syncthreads();
      if constexpr (WS) {
#pragma unroll
        for (int i = 0; i < 4; ++i) {
          const int s = (w * 4 + i) * 64 + l;
          const int col = s >> 3, sl = s & 7;
          const __bf16* src =
              cbf + (size_t)(col0 + col) * D_K + kt * BK + ((sl ^ (col & 7)) << 3);
          __builtin_amdgcn_global_load_lds(
              (const AS1 unsigned int*)(const void*)src,
              (AS3 unsigned int*)(void*)(Bb + (w * 4 + i) * 1024), 16, 0, 0);
        }
      } else {
#pragma unroll
        for (int c = 0; c < 8; ++c) {
          const int f = c * 256 + t;
          const int col = f >> 4, kq = f & 15;
          const float4 v = *reinterpret_cast<const float4*>(
              centf + (size_t)(col0 + col) * D_K + kt * BK + kq * 4);
          cpart[c] += v.x * v.x + v.y * v.y + v.z * v.z + v.w * v.w;
          bf16x4 o = {(__bf16)v.x, (__bf16)v.y, (__bf16)v.z, (__bf16)v.w};
          const int slot = kq >> 1;
          *reinterpret_cast<bf16x4*>(Bb + col * 128 + ((slot ^ (col & 7)) << 4) +
                                     (kq & 1) * 8) = o;
        }
      }
#pragma unroll
      for (int c = 0; c < 8; ++c) {
        const int f = c * 256 + t;
        const int row = f >> 4, kq = f & 15;
        const float4 v = *reinterpret_cast<const float4*>(
            embeds + (row0 + row) * (long)D_K + kt * BK + kq * 4);
        if (nt == 0) sqpart[c] += v.x * v.x + v.y * v.y + v.z * v.z + v.w * v.w;
        bf16x4 o = {(__bf16)v.x, (__bf16)v.y, (__bf16)v.z, (__bf16)v.w};
        const int slot = kq >> 1;
        *reinterpret_cast<bf16x4*>(Ab + row * 128 + ((slot ^ (row & 7)) << 4) +
                                   (kq & 1) * 8) = o;
      }
      __syncthreads();
#pragma unroll
      for (int ks = 0; ks < 2; ++ks) {
        bf16x8 af[4], bfr[4];
#pragma unroll
        for (int m = 0; m < 4; ++m) {
          const int row = wr * 64 + m * 16 + lr;
          const int slot = ks * 4 + g;
          af[m] = *reinterpret_cast<const bf16x8*>(Ab + row * 128 +
                                                   ((slot ^ (row & 7)) << 4));
        }
#pragma unroll
        for (int n = 0; n < 4; ++n) {
          const int col = wc * 64 + n * 16 + lr;
          const int slot = ks * 4 + g;
          bfr[n] = *reinterpret_cast<const bf16x8*>(Bb + col * 128 +
                                                    ((slot ^ (col & 7)) << 4));
        }
#pragma unroll
        for (int m = 0; m < 4; ++m)
#pragma unroll
          for (int n = 0; n < 4; ++n)
            acc[m][n] =
                __builtin_amdgcn_mfma_f32_16x16x32_bf16(af[m], bfr[n], acc[m][n], 0, 0, 0);
      }
    }

    if (nt == 0) {
#pragma unroll
      for (int c = 0; c < 8; ++c) {
        float ss = sqpart[c];
        ss += __shfl_xor(ss, 1);
        ss += __shfl_xor(ss, 2);
        ss += __shfl_xor(ss, 4);
        ss += __shfl_xor(ss, 8);
        if (lr == 0) sqrow[c * 16 + (w * 4 + g)] = ss;
      }
    }
    if constexpr (!WS) {
#pragma unroll
      for (int c = 0; c < 8; ++c) {
        float ss = cpart[c];
        ss += __shfl_xor(ss, 1);
        ss += __shfl_xor(ss, 2);
        ss += __shfl_xor(ss, 4);
        ss += __shfl_xor(ss, 8);
        if (lr == 0) colsq[c * 16 + (w * 4 + g)] = ss;
      }
      __syncthreads();
    }

#pragma unroll
    for (int n = 0; n < 4; ++n) {
      float cs;
      if constexpr (WS)
        cs = csq[col0 + wc * 64 + n * 16 + lr];
      else
        cs = colsq[wc * 64 + n * 16 + lr];
#pragma unroll
      for (int m = 0; m < 4; ++m)
#pragma unroll
        for (int r = 0; r < 4; ++r)
          runmin[m][r] = fminf(runmin[m][r], cs - 2.0f * acc[m][n][r]);
    }
  }

#pragma unroll
  for (int m = 0; m < 4; ++m)
#pragma unroll
    for (int r = 0; r < 4; ++r) {
      float v = runmin[m][r];
      v = fminf(v, __shfl_xor(v, 1));
      v = fminf(v, __shfl_xor(v, 2));
      v = fminf(v, __shfl_xor(v, 4));
      v = fminf(v, __shfl_xor(v, 8));
      runmin[m][r] = v;
    }
  if (lr == 0) {
#pragma unroll
    for (int m = 0; m < 4; ++m)
#pragma unroll
      for (int r = 0; r < 4; ++r)
        rowmin2[wc][wr * 64 + m * 16 + g * 4 + r] = runmin[m][r];
  }
  __syncthreads();
  if (t < TM) {
    const float v = fminf(rowmin2[0][t], rowmin2[1][t]);
    out[row0 + t] = sqrtf(fmaxf(sqrow[t] + v, 0.f));
  }
}

extern "C" void kernel_launch(void* const* d_in, const int* in_sizes, int n_in,
                              void* d_out, int out_size, void* d_ws, size_t ws_size,
                              hipStream_t stream) {
  const float* embeds = (const float*)d_in[0];
  const float* cent = (const float*)d_in[1];
  float* out = (float*)d_out;

  // ws layout for the fp8 fast path (~112 MiB)
  const size_t off_c8 = 0;
  const size_t off_csq = off_c8 + (size_t)M_CENT * D_K;             // 2 MiB
  const size_t off_e8 = off_csq + (size_t)M_CENT * 4;               // +8 KiB
  const size_t off_esq = off_e8 + (size_t)N_ROWS * D_K;             // +98 MiB
  const size_t off_pmin = off_esq + (size_t)N_ROWS * 4;             // +392 KiB
  const size_t need_full = off_pmin + (size_t)N_ROWS * NCT4 * 4;    // +6.1 MiB
  const size_t need_small = (size_t)M_CENT * D_K * 2 + (size_t)M_CENT * 4;

  if (ws_size >= need_full) {
    unsigned char* c8 = (unsigned char*)d_ws + off_c8;
    float* csq = (float*)((char*)d_ws + off_csq);
    unsigned char* e8 = (unsigned char*)d_ws + off_e8;
    float* esq = (float*)((char*)d_ws + off_esq);
    float* pmin = (float*)((char*)d_ws + off_pmin);
    rowsq_fp8pack<<<M_CENT, 256, 0, stream>>>(cent, c8, csq);
    rowsq_fp8pack<<<N_ROWS, 256, 0, stream>>>(embeds, e8, esq);
    gemm_min_fp8<<<NBLK4, 256, 0, stream>>>(e8, c8, csq, pmin);
    final_min<<<N_ROWS / 256, 256, 0, stream>>>(esq, pmin, out);
  } else if (ws_size >= need_small) {
    __bf16* cbf = (__bf16*)d_ws;
    float* csq = (float*)((char*)d_ws + (size_t)M_CENT * D_K * 2);
    rowsq_bf16<<<M_CENT, 256, 0, stream>>>(cent, cbf, csq);
    fused_min<true><<<N_ROWS / TM, 256, 0, stream>>>(embeds, cent, cbf, csq, out);
  } else {
    fused_min<false><<<N_ROWS / TM, 256, 0, stream>>>(embeds, cent, nullptr, nullptr, out);
  }
}